// Round 3
// baseline (2371.735 us; speedup 1.0000x reference)
//
#include <hip/hip_runtime.h>
#include <cstdint>
#include <cstddef>

// ---------------------------------------------------------------------------
// Equivariant graph conv block, MI355X (gfx950).
//   k_prep : out=b_lin; mkey=0; denom=0; W2t/r2t/Wlt bf16 transposed copies
//   k_msg  : msg = concat(src,dst,ele)@W_pre (bf16); h_gate = silu(ele@r1+rb1)
//   k_attn : logits (LN-MLP) + per-dst atomicMax
//   k_ea   : ea = exp(logit - m[dst]); atomicAdd denom
//   k_norm : alpha = ea / denom[dst]
//   k_fused: per [128e x 256o] half: scale=(hgate@r2+rb2)*alpha (MFMA, regs)
//            value=(msg ox sh)@W_tp2 (MFMA K=1024, dbuf pipeline, 1 barrier/ks)
//            vs=value*scale -> LDS -> partial vs@W_lin (MFMA) -> atomics
// ---------------------------------------------------------------------------

typedef unsigned int u32;
typedef unsigned short u16;
typedef __attribute__((ext_vector_type(8))) short short8;
typedef __attribute__((ext_vector_type(4))) float f32x4;
typedef __attribute__((ext_vector_type(4))) u32 u32x4;

__device__ __forceinline__ float bf2f(u16 u){ return __uint_as_float(((u32)u)<<16); }
__device__ __forceinline__ u16 f2bf(float f){
  u32 i = __float_as_uint(f);
  u32 r = i + 0x7FFFu + ((i>>16)&1u);
  return (u16)(r>>16);
}
__device__ __forceinline__ u32 pk2(float a, float b){
  return (u32)f2bf(a) | ((u32)f2bf(b)<<16);
}
__device__ __forceinline__ u32 cvtpk(float a, float b){
  u32 r;
  asm("v_cvt_pk_bf16_f32 %0, %1, %2" : "=v"(r) : "v"(a), "v"(b));
  return r;
}
__device__ __forceinline__ void atomAddF(float* p, float v){
  asm volatile("global_atomic_add_f32 %0, %1, off" :: "v"(p), "v"(v) : "memory");
}
__device__ __forceinline__ void gl2lds(const void* g, void* l){
  __builtin_amdgcn_global_load_lds((const __attribute__((address_space(1))) u32*)g,
                                   (__attribute__((address_space(3))) u32*)l, 16, 0, 0);
}
__device__ __forceinline__ float decm(u32 k){
  u32 b = (k & 0x80000000u) ? (k & 0x7FFFFFFFu) : ~k;
  return __uint_as_float(b);
}

// ---------------------------------------------------------------------------
__global__ void k_prep(float* __restrict__ out, const float* __restrict__ bl,
                       u32* __restrict__ mkey, float* __restrict__ denom,
                       const float* __restrict__ W2, u16* __restrict__ w2t,
                       const float* __restrict__ r2, u16* __restrict__ r2t,
                       const float* __restrict__ Wl, u16* __restrict__ wlt)
{
  int t = blockIdx.x*256 + threadIdx.x;
  if (t < 1048576){ out[t] = bl[t&63]; return; }
  t -= 1048576;
  if (t < 131072){ mkey[t] = 0u; return; }
  t -= 131072;
  if (t < 131072){ denom[t] = 0.f; return; }
  t -= 131072;
  if (t < 65536){ // w2t[o][k] = W_tp2[k][o], row stride 2048B
    int o = t & 511, kc = t >> 9;
    u32x4 v;
    v.x = pk2(W2[(size_t)(kc*8+0)*512+o], W2[(size_t)(kc*8+1)*512+o]);
    v.y = pk2(W2[(size_t)(kc*8+2)*512+o], W2[(size_t)(kc*8+3)*512+o]);
    v.z = pk2(W2[(size_t)(kc*8+4)*512+o], W2[(size_t)(kc*8+5)*512+o]);
    v.w = pk2(W2[(size_t)(kc*8+6)*512+o], W2[(size_t)(kc*8+7)*512+o]);
    *(u32x4*)((char*)w2t + (size_t)o*2048 + kc*16) = v;
    return;
  }
  t -= 65536;
  if (t < 4096){ // r2t[o][k] = r2[k][o], row stride 128B
    int o = t & 511, kc = t >> 9;
    u32x4 v;
    v.x = pk2(r2[(size_t)(kc*8+0)*512+o], r2[(size_t)(kc*8+1)*512+o]);
    v.y = pk2(r2[(size_t)(kc*8+2)*512+o], r2[(size_t)(kc*8+3)*512+o]);
    v.z = pk2(r2[(size_t)(kc*8+4)*512+o], r2[(size_t)(kc*8+5)*512+o]);
    v.w = pk2(r2[(size_t)(kc*8+6)*512+o], r2[(size_t)(kc*8+7)*512+o]);
    *(u32x4*)((char*)r2t + (size_t)o*128 + kc*16) = v;
    return;
  }
  t -= 4096;
  { // wlt[j][k] = W_lin[k][j], row stride 1024B
    int j = t & 63, kc = t >> 6;
    u32x4 v;
    v.x = pk2(Wl[(size_t)(kc*8+0)*64+j], Wl[(size_t)(kc*8+1)*64+j]);
    v.y = pk2(Wl[(size_t)(kc*8+2)*64+j], Wl[(size_t)(kc*8+3)*64+j]);
    v.z = pk2(Wl[(size_t)(kc*8+4)*64+j], Wl[(size_t)(kc*8+5)*64+j]);
    v.w = pk2(Wl[(size_t)(kc*8+6)*64+j], Wl[(size_t)(kc*8+7)*64+j]);
    *(u32x4*)((char*)wlt + (size_t)j*1024 + kc*16) = v;
  }
}

// ---------------------------------------------------------------------------
#define GEMV4(ACC, X, WBASE)                                                       \
  { const float* w_ = (WBASE);                                                     \
    _Pragma("unroll") for (int j=0;j<64;j++) ACC[j] = fmaf((X).x, w_[j],     ACC[j]); \
    _Pragma("unroll") for (int j=0;j<64;j++) ACC[j] = fmaf((X).y, w_[64+j],  ACC[j]); \
    _Pragma("unroll") for (int j=0;j<64;j++) ACC[j] = fmaf((X).z, w_[128+j], ACC[j]); \
    _Pragma("unroll") for (int j=0;j<64;j++) ACC[j] = fmaf((X).w, w_[192+j], ACC[j]); }

__global__ __launch_bounds__(256) void k_msg(
    const float* __restrict__ nf, const float* __restrict__ eleg,
    const int* __restrict__ esrc, const int* __restrict__ edst,
    const float* __restrict__ Wp, const float* __restrict__ bp,
    const float* __restrict__ r1, const float* __restrict__ rb1,
    u16* __restrict__ msgb, u16* __restrict__ hgb)
{
  const int e = blockIdx.x*256 + threadIdx.x;
  const int src = esrc[e];
  const int dst = edst[e];
  const float4* sr4 = (const float4*)(nf + (size_t)src*64);
  const float4* dr4 = (const float4*)(nf + (size_t)dst*64);
  const float4* er4 = (const float4*)(eleg + (size_t)e*64);

  float acc[64];
  #pragma unroll
  for (int j=0;j<64;j++) acc[j] = bp[j];
  for (int ic=0; ic<16; ++ic){ float4 x = sr4[ic]; GEMV4(acc, x, Wp + ic*256); }
  for (int ic=0; ic<16; ++ic){ float4 x = dr4[ic]; GEMV4(acc, x, Wp + 4096 + ic*256); }
  for (int ic=0; ic<16; ++ic){ float4 x = er4[ic]; GEMV4(acc, x, Wp + 8192 + ic*256); }
  {
    u32x4* md = (u32x4*)(msgb + (size_t)e*64);
    #pragma unroll
    for (int c=0;c<8;c++){
      u32x4 v;
      v.x = cvtpk(acc[8*c+0],acc[8*c+1]); v.y = cvtpk(acc[8*c+2],acc[8*c+3]);
      v.z = cvtpk(acc[8*c+4],acc[8*c+5]); v.w = cvtpk(acc[8*c+6],acc[8*c+7]);
      md[c] = v;
    }
  }
  // h_gate = silu(ele@r1 + rb1)
  #pragma unroll
  for (int j=0;j<64;j++) acc[j] = rb1[j];
  for (int ic=0; ic<16; ++ic){ float4 x = er4[ic]; GEMV4(acc, x, r1 + ic*256); }
  #pragma unroll
  for (int j=0;j<64;j++) acc[j] = acc[j] / (1.f + __expf(-acc[j]));
  {
    u32x4* hd = (u32x4*)(hgb + (size_t)e*64);
    #pragma unroll
    for (int c=0;c<8;c++){
      u32x4 v;
      v.x = cvtpk(acc[8*c+0],acc[8*c+1]); v.y = cvtpk(acc[8*c+2],acc[8*c+3]);
      v.z = cvtpk(acc[8*c+4],acc[8*c+5]); v.w = cvtpk(acc[8*c+6],acc[8*c+7]);
      hd[c] = v;
    }
  }
}

__global__ __launch_bounds__(256) void k_attn(
    const float* __restrict__ eleg, const int* __restrict__ edst,
    const float* __restrict__ a1, const float* __restrict__ ab1,
    const float* __restrict__ g1, const float* __restrict__ be1,
    const float* __restrict__ a2, const float* __restrict__ ab2,
    const float* __restrict__ g2, const float* __restrict__ be2,
    const float* __restrict__ a3, const float* __restrict__ ab3,
    float* __restrict__ eab, u32* __restrict__ mkey)
{
  const int e = blockIdx.x*256 + threadIdx.x;
  const int dst = edst[e];
  const float4* er4 = (const float4*)(eleg + (size_t)e*64);

  // u1 = silu(LN(ele@a1 + ab1, g1, be1))
  float u[64];
  #pragma unroll
  for (int j=0;j<64;j++) u[j] = ab1[j];
  for (int ic=0; ic<16; ++ic){ float4 x = er4[ic]; GEMV4(u, x, a1 + ic*256); }
  {
    float s = 0.f;
    #pragma unroll
    for (int j=0;j<64;j++) s += u[j];
    float mu = s * 0.015625f;
    float s2 = 0.f;
    #pragma unroll
    for (int j=0;j<64;j++){ float d = u[j]-mu; s2 = fmaf(d,d,s2); }
    float rs = rsqrtf(s2*0.015625f + 1e-6f);
    #pragma unroll
    for (int j=0;j<64;j++){
      float y = (u[j]-mu)*rs*g1[j] + be1[j];
      u[j] = y / (1.f + __expf(-y));
    }
  }
  // u2 = silu(LN(u1@a2 + ab2, g2, be2))   (static indexing: full unroll)
  float v[64];
  #pragma unroll
  for (int j=0;j<64;j++) v[j] = ab2[j];
  #pragma unroll
  for (int i=0;i<64;i++){
    float x = u[i];
    const float* w = a2 + i*64;
    #pragma unroll
    for (int j=0;j<64;j++) v[j] = fmaf(x, w[j], v[j]);
  }
  {
    float s = 0.f;
    #pragma unroll
    for (int j=0;j<64;j++) s += v[j];
    float mu = s * 0.015625f;
    float s2 = 0.f;
    #pragma unroll
    for (int j=0;j<64;j++){ float d = v[j]-mu; s2 = fmaf(d,d,s2); }
    float rs = rsqrtf(s2*0.015625f + 1e-6f);
    #pragma unroll
    for (int j=0;j<64;j++){
      float y = (v[j]-mu)*rs*g2[j] + be2[j];
      v[j] = y / (1.f + __expf(-y));
    }
  }
  // logits
  float l[8];
  #pragma unroll
  for (int h=0;h<8;h++) l[h] = ab3[h];
  #pragma unroll
  for (int i=0;i<64;i++){
    float x = v[i];
    #pragma unroll
    for (int h=0;h<8;h++) l[h] = fmaf(x, a3[i*8+h], l[h]);
  }
  float4* ld = (float4*)(eab + (size_t)e*8);
  ld[0] = make_float4(l[0],l[1],l[2],l[3]);
  ld[1] = make_float4(l[4],l[5],l[6],l[7]);
  #pragma unroll
  for (int h=0;h<8;h++){
    u32 b = __float_as_uint(l[h]);
    u32 k = (b & 0x80000000u) ? ~b : (b | 0x80000000u);
    atomicMax(&mkey[(size_t)dst*8 + h], k);
  }
}

// ---------------------------------------------------------------------------
__global__ void k_ea(const int* __restrict__ edst, float* __restrict__ eab,
                     const u32* __restrict__ mkey, float* __restrict__ denom)
{
  int e = blockIdx.x*256 + threadIdx.x;
  int dst = edst[e];
  float4 l0 = ((const float4*)(eab + (size_t)e*8))[0];
  float4 l1 = ((const float4*)(eab + (size_t)e*8))[1];
  uint4 k0 = ((const uint4*)(mkey + (size_t)dst*8))[0];
  uint4 k1 = ((const uint4*)(mkey + (size_t)dst*8))[1];
  float e0 = __expf(l0.x - decm(k0.x));
  float e1 = __expf(l0.y - decm(k0.y));
  float e2 = __expf(l0.z - decm(k0.z));
  float e3 = __expf(l0.w - decm(k0.w));
  float e4 = __expf(l1.x - decm(k1.x));
  float e5 = __expf(l1.y - decm(k1.y));
  float e6 = __expf(l1.z - decm(k1.z));
  float e7 = __expf(l1.w - decm(k1.w));
  ((float4*)(eab + (size_t)e*8))[0] = make_float4(e0,e1,e2,e3);
  ((float4*)(eab + (size_t)e*8))[1] = make_float4(e4,e5,e6,e7);
  float* dn = denom + (size_t)dst*8;
  atomAddF(dn+0,e0); atomAddF(dn+1,e1); atomAddF(dn+2,e2); atomAddF(dn+3,e3);
  atomAddF(dn+4,e4); atomAddF(dn+5,e5); atomAddF(dn+6,e6); atomAddF(dn+7,e7);
}

__global__ void k_norm(const int* __restrict__ edst, float* __restrict__ eab,
                       const float* __restrict__ denom)
{
  int e = blockIdx.x*256 + threadIdx.x;
  int dst = edst[e];
  float4 a0 = ((const float4*)(eab + (size_t)e*8))[0];
  float4 a1 = ((const float4*)(eab + (size_t)e*8))[1];
  float4 d0 = ((const float4*)(denom + (size_t)dst*8))[0];
  float4 d1 = ((const float4*)(denom + (size_t)dst*8))[1];
  ((float4*)(eab + (size_t)e*8))[0] = make_float4(a0.x/d0.x, a0.y/d0.y, a0.z/d0.z, a0.w/d0.w);
  ((float4*)(eab + (size_t)e*8))[1] = make_float4(a1.x/d1.x, a1.y/d1.y, a1.z/d1.z, a1.w/d1.w);
}

// ---------------------------------------------------------------------------
// Fused: per block 128 edges x full 512 outputs (2 halves of 256 cols).
// 512 thr = 8 waves; wave (wm=wave>>2, wn=wave&3) owns 64e x 64o of each half.
#define FORM_A(KSP, AN) {                                                        \
  float f0_ = bf2f((u16)((mrow[KSP]>>mshift)&0xFFFFu));                          \
  u32x4 w0_, w1_;                                                                \
  w0_.x=cvtpk(f0_*shr[0], f0_*shr[1]);  w0_.y=cvtpk(f0_*shr[2], f0_*shr[3]);     \
  w0_.z=cvtpk(f0_*shr[4], f0_*shr[5]);  w0_.w=cvtpk(f0_*shr[6], f0_*shr[7]);     \
  w1_.x=cvtpk(f0_*shr[8], f0_*shr[9]);  w1_.y=cvtpk(f0_*shr[10],f0_*shr[11]);    \
  w1_.z=cvtpk(f0_*shr[12],f0_*shr[13]); w1_.w=cvtpk(f0_*shr[14],f0_*shr[15]);    \
  char* b_ = (AN) + erow*128; int r7_ = erow&7;                                  \
  *(u32x4*)(b_ + (((t4*2+0)^r7_)*16)) = w0_;                                     \
  *(u32x4*)(b_ + (((t4*2+1)^r7_)*16)) = w1_; }

__global__ __launch_bounds__(512,2) void k_fused(
    const u16* __restrict__ msgb, const float* __restrict__ shg,
    const u16* __restrict__ w2t, const u16* __restrict__ hgb,
    const u16* __restrict__ r2t, const float* __restrict__ rb2,
    const float* __restrict__ alpha, const u16* __restrict__ wlt,
    const int* __restrict__ edst, float* __restrict__ out)
{
  __shared__ char lds[98304];
  const int tid = threadIdx.x;
  const int e0 = blockIdx.x*128;
  const int wave = tid>>6, lane = tid&63;
  const int wm = wave>>2, wn = wave&3;
  const int wub = (tid&448)*16;     // wave-uniform LDS base for gl2lds
  char* A0 = lds;          // 16KB
  char* A1 = lds+16384;    // 16KB
  char* B0 = lds+32768;    // 32KB
  char* B1 = lds+65536;    // 32KB

  const int erow = tid>>2, t4 = tid&3;
  const int et = e0 + erow;
  u32 mrow[16];
  {
    const u32* mp32 = (const u32*)(msgb + (size_t)et*64);
    #pragma unroll
    for (int ks=0; ks<16; ++ks) mrow[ks] = mp32[ks*2 + (t4>>1)];
  }
  const int mshift = (t4&1)*16;
  float shr[16];
  {
    const float4* sp = (const float4*)(shg + (size_t)et*16);
    float4 s0=sp[0], s1=sp[1], s2=sp[2], s3=sp[3];
    shr[0]=s0.x; shr[1]=s0.y; shr[2]=s0.z; shr[3]=s0.w;
    shr[4]=s1.x; shr[5]=s1.y; shr[6]=s1.z; shr[7]=s1.w;
    shr[8]=s2.x; shr[9]=s2.y; shr[10]=s2.z; shr[11]=s2.w;
    shr[12]=s3.x; shr[13]=s3.y; shr[14]=s3.z; shr[15]=s3.w;
  }

  f32x4 acc_o[4];
  #pragma unroll
  for (int n=0;n<4;n++) acc_o[n] = (f32x4){0.f,0.f,0.f,0.f};

  #pragma unroll 1
  for (int jbo=0; jbo<2; ++jbo){
    const int j0 = jbo*256;
    __syncthreads();                 // prior half's LDS reads all done
    // ---- stage scale-GEMM operands: hgb [128][64] -> A0, r2t [256][64] -> B0
    #pragma unroll
    for (int c=0;c<2;c++){
      int cid=c*512+tid, row=cid>>3, ch=cid&7;
      gl2lds((const char*)hgb + (size_t)(e0+row)*128 + ((ch^(row&7))*16),
             A0 + c*8192 + wub);
    }
    #pragma unroll
    for (int c=0;c<4;c++){
      int cid=c*512+tid, row=cid>>3, ch=cid&7;
      gl2lds((const char*)r2t + (size_t)(j0+row)*128 + ((ch^(row&7))*16),
             B0 + c*8192 + wub);
    }
    __syncthreads();

    // ---- scale GEMM (K=64) -> scale regs ----
    f32x4 scale[4][4];
    {
      f32x4 accs[4][4];
      #pragma unroll
      for (int a=0;a<4;a++)
        #pragma unroll
        for (int b=0;b<4;b++) accs[a][b] = (f32x4){0.f,0.f,0.f,0.f};
      #pragma unroll
      for (int kk=0;kk<2;kk++){
        short8 af[4], bfv[4];
        int kc = kk*4 + (lane>>4);
        #pragma unroll
        for (int mt=0;mt<4;mt++){
          int r = wm*64 + mt*16 + (lane&15);
          af[mt] = *(const short8*)(A0 + r*128 + ((kc ^ (r&7))*16));
        }
        #pragma unroll
        for (int nt=0;nt<4;nt++){
          int r = wn*64 + nt*16 + (lane&15);
          bfv[nt] = *(const short8*)(B0 + r*128 + ((kc ^ (r&7))*16));
        }
        #pragma unroll
        for (int mt=0;mt<4;mt++)
          #pragma unroll
          for (int nt=0;nt<4;nt++)
            accs[mt][nt] = __builtin_amdgcn_mfma_f32_16x16x32_bf16(af[mt], bfv[nt], accs[mt][nt], 0,0,0);
      }
      const int h = jbo*4 + wn;
      float alv[4][4];
      #pragma unroll
      for (int mt=0;mt<4;mt++)
        #pragma unroll
        for (int q=0;q<4;q++){
          int row = wm*64 + mt*16 + (lane>>4)*4 + q;
          alv[mt][q] = alpha[(size_t)(e0+row)*8 + h];
        }
      float rbv[4];
      #pragma unroll
      for (int nt=0;nt<4;nt++) rbv[nt] = rb2[j0 + wn*64 + nt*16 + (lane&15)];
      #pragma unroll
      for (int mt=0;mt<4;mt++)
        #pragma unroll
        for (int nt=0;nt<4;nt++)
          #pragma unroll
          for (int q=0;q<4;q++)
            scale[mt][nt][q] = (accs[mt][nt][q] + rbv[nt]) * alv[mt][q];
    }
    __syncthreads();                 // scale-GEMM LDS reads done; A0/B0 free

    // ---- value GEMM pipeline prologue: A(0)->A0, B(0)->B0 ----
    FORM_A(0, A0);
    #pragma unroll
    for (int c=0;c<4;c++){
      int cid=c*512+tid, row=cid>>3, ch=cid&7;
      gl2lds((const char*)w2t + (size_t)(j0+row)*2048 + 0*128 + ((ch^(row&7))*16),
             B0 + c*8192 + wub);
    }
    __syncthreads();                 // (full vmcnt/lgkm drain at barrier)

    // ---- value GEMM main loop: 1 barrier/ks, prefetch distance 1 ----
    f32x4 accv[4][4];
    #pragma unroll
    for (int a=0;a<4;a++)
      #pragma unroll
      for (int b=0;b<4;b++) accv[a][b] = (f32x4){0.f,0.f,0.f,0.f};

    #pragma unroll
    for (int ks=0; ks<16; ++ks){
      char* Ac = (ks&1) ? A1 : A0;
      char* Bc = (ks&1) ? B1 : B0;
      char* An = (ks&1) ? A0 : A1;
      char* Bn = (ks&1) ? B0 : B1;
      if (ks < 15){
        #pragma unroll
        for (int c=0;c<4;c++){      // prefetch B(ks+1)
          int cid=c*512+tid, row=cid>>3, ch=cid&7;
          gl2lds((const char*)w2t + (size_t)(j0+row)*2048 + (ks+1)*128 + ((ch^(row&7))*16),
                 Bn + c*8192 + wub);
        }
        FORM_A(ks+1, An);           // form A(ks+1) in regs -> ds_write
      }
      #pragma unroll
      for (int kk=0;kk<2;kk++){
        short8 af[4], bfv[4];
        int kc = kk*4 + (lane>>4);
        #pragma unroll
        for (int mt=0;mt<4;mt++){
          int r = wm*64 + mt*16 + (lane&15);
          af[mt] = *(const short8*)(Ac + r*128 + ((kc ^ (r&7))*16));
        }
        #pragma unroll
        for (int nt=0;nt<4;nt++){
          int r = wn*64 + nt*16 + (lane&15);
          bfv[nt] = *(const short8*)(Bc + r*128 + ((kc ^ (r&7))*16));
        }
        __builtin_amdgcn_s_setprio(1);
        #pragma unroll
        for (int mt=0;mt<4;mt++)
          #pragma unroll
          for (int nt=0;nt<4;nt++)
            accv[mt][nt] = __builtin_amdgcn_mfma_f32_16x16x32_bf16(af[mt], bfv[nt], accv[mt][nt], 0,0,0);
        __builtin_amdgcn_s_setprio(0);
      }
      __syncthreads();               // drains vmcnt(0)+lgkm(0): B(ks+1)/A(ks+1) ready
    }

    // ---- vs = accv*scale -> LDS [128][256] bf16 (64KB, reuse A0..B0) ----
    #pragma unroll
    for (int mt=0;mt<4;mt++)
      #pragma unroll
      for (int nt=0;nt<4;nt++){
        int col = wn*64 + nt*16 + (lane&15);
        int c16 = col>>3, cby = (col&7)*2;
        #pragma unroll
        for (int q=0;q<4;q++){
          int row = wm*64 + mt*16 + (lane>>4)*4 + q;
          *(u16*)(lds + row*512 + ((c16 ^ ((row&7)<<1))*16) + cby) =
              f2bf(accv[mt][nt][q] * scale[mt][nt][q]);
        }
      }
    __syncthreads();

    // ---- partial vs@W_lin (K=256), accumulate across halves ----
    #pragma unroll
    for (int kk=0;kk<8;kk++){
      short8 a2f;
      {
        int r = wave*16 + (lane&15);
        int kc = kk*4 + (lane>>4);
        a2f = *(const short8*)(lds + r*512 + ((kc ^ ((r&7)<<1))*16));
      }
      #pragma unroll
      for (int nt=0;nt<4;nt++){
        int j = nt*16 + (lane&15);
        int k = j0 + kk*32 + (lane>>4)*8;
        short8 b2f = *(const short8*)((const char*)wlt + (size_t)j*1024 + (size_t)k*2);
        acc_o[nt] = __builtin_amdgcn_mfma_f32_16x16x32_bf16(a2f, b2f, acc_o[nt], 0,0,0);
      }
    }
  }

  // ---- scatter into out[dst] ----
  #pragma unroll
  for (int q=0;q<4;q++){
    int r = wave*16 + (lane>>4)*4 + q;
    int n = edst[e0 + r];
    float* basep = out + (size_t)n*64;
    #pragma unroll
    for (int nt=0;nt<4;nt++){
      int col = nt*16 + (lane&15);
      atomAddF(basep + col, acc_o[nt][q]);
    }
  }
}

// ---------------------------------------------------------------------------
extern "C" void kernel_launch(void* const* d_in, const int* in_sizes, int n_in,
                              void* d_out, int out_size, void* d_ws, size_t ws_size,
                              hipStream_t stream)
{
  const float* nf  = (const float*)d_in[0];
  const float* shg = (const float*)d_in[1];
  const float* ele = (const float*)d_in[2];
  const int* esrc  = (const int*)d_in[3];
  const int* edst  = (const int*)d_in[4];
  const float* Wp  = (const float*)d_in[6];
  const float* bp  = (const float*)d_in[7];
  const float* W2  = (const float*)d_in[8];
  const float* r1  = (const float*)d_in[9];
  const float* rb1 = (const float*)d_in[10];
  const float* r2  = (const float*)d_in[11];
  const float* rb2 = (const float*)d_in[12];
  const float* a1  = (const float*)d_in[13];
  const float* ab1 = (const float*)d_in[14];
  const float* g1  = (const float*)d_in[15];
  const float* be1 = (const float*)d_in[16];
  const float* a2  = (const float*)d_in[17];
  const float* ab2 = (const float*)d_in[18];
  const float* g2  = (const float*)d_in[19];
  const float* be2 = (const float*)d_in[20];
  const float* a3  = (const float*)d_in[21];
  const float* ab3 = (const float*)d_in[22];
  const float* Wl  = (const float*)d_in[23];
  const float* bl  = (const float*)d_in[24];
  float* out = (float*)d_out;
  char* ws = (char*)d_ws;

  u16* msgb    = (u16*)(ws + 0);            // E*64 bf16 = 32MB
  u16* hgb     = (u16*)(ws + 33554432);     // E*64 bf16 = 32MB
  float* eab   = (float*)(ws + 67108864);   // E*8 f32 = 8MB (logits->ea->alpha)
  u32* mkey    = (u32*)(ws + 75497472);     // N*8 u32 = 512KB
  float* denom = (float*)(ws + 76021760);   // N*8 f32 = 512KB
  u16* w2t     = (u16*)(ws + 76546048);     // 512x1024 bf16 = 1MB
  u16* r2t     = (u16*)(ws + 77594624);     // 512x64 bf16 = 64KB
  u16* wlt     = (u16*)(ws + 77660160);     // 64x512 bf16 = 64KB
  // total ~74.1 MB

  k_prep<<<5408,256,0,stream>>>(out, bl, mkey, denom, W2, w2t, r2, r2t, Wl, wlt);
  k_msg<<<1024,256,0,stream>>>(nf, ele, esrc, edst, Wp, bp, r1, rb1, msgb, hgb);
  k_attn<<<1024,256,0,stream>>>(ele, edst, a1, ab1, g1, be1, a2, ab2, g2, be2,
                                a3, ab3, eab, mkey);
  k_ea<<<1024,256,0,stream>>>(edst, eab, mkey, denom);
  k_norm<<<1024,256,0,stream>>>(edst, eab, denom);
  k_fused<<<2048,512,0,stream>>>(msgb, shg, w2t, hgb, r2t, rb2, eab, wlt, edst, out);
}

// Round 4
// 1078.514 us; speedup vs baseline: 2.1991x; 2.1991x over previous
//
#include <hip/hip_runtime.h>
#include <cstdint>
#include <cstddef>

// ---------------------------------------------------------------------------
// Equivariant graph conv block, MI355X (gfx950).
//   k_prep : out=b_lin; mkey=0; denom=0; W2t/r2t/Wlt bf16 transposed copies
//   k_msg  : msg = concat(src,dst,ele)@W_pre (bf16); h_gate = silu(ele@r1+rb1)
//   k_attn : logits (LN-MLP) + per-dst atomicMax
//   k_ea   : ea = exp(logit - m[dst]); atomicAdd denom
//   k_norm : alpha = ea / denom[dst]
//   k_fused: per [128e x 128o] col-block (x4): scale=(hgate@r2+rb2)*alpha (regs)
//            value=(msg ox sh)@W_tp2, K=1024, DOUBLE-BUFFERED prefetch-dist-1
//            vs=value*scale -> LDS -> partial vs@W_lin -> fp32 atomics
//   VGPR discipline: per-wave 64x32 tile (scale[4][2]+accv[4][2]) -> fits 128
//   VGPRs at __launch_bounds__(512,2). 64x64 tiles spill (round-3 regression).
// ---------------------------------------------------------------------------

typedef unsigned int u32;
typedef unsigned short u16;
typedef __attribute__((ext_vector_type(8))) short short8;
typedef __attribute__((ext_vector_type(4))) float f32x4;
typedef __attribute__((ext_vector_type(4))) u32 u32x4;

__device__ __forceinline__ float bf2f(u16 u){ return __uint_as_float(((u32)u)<<16); }
__device__ __forceinline__ u16 f2bf(float f){
  u32 i = __float_as_uint(f);
  u32 r = i + 0x7FFFu + ((i>>16)&1u);
  return (u16)(r>>16);
}
__device__ __forceinline__ u32 pk2(float a, float b){
  return (u32)f2bf(a) | ((u32)f2bf(b)<<16);
}
__device__ __forceinline__ u32 cvtpk(float a, float b){
  u32 r;
  asm("v_cvt_pk_bf16_f32 %0, %1, %2" : "=v"(r) : "v"(a), "v"(b));
  return r;
}
__device__ __forceinline__ void atomAddF(float* p, float v){
  asm volatile("global_atomic_add_f32 %0, %1, off" :: "v"(p), "v"(v) : "memory");
}
__device__ __forceinline__ void gl2lds(const void* g, void* l){
  __builtin_amdgcn_global_load_lds((const __attribute__((address_space(1))) u32*)g,
                                   (__attribute__((address_space(3))) u32*)l, 16, 0, 0);
}
__device__ __forceinline__ float decm(u32 k){
  u32 b = (k & 0x80000000u) ? (k & 0x7FFFFFFFu) : ~k;
  return __uint_as_float(b);
}

// ---------------------------------------------------------------------------
__global__ void k_prep(float* __restrict__ out, const float* __restrict__ bl,
                       u32* __restrict__ mkey, float* __restrict__ denom,
                       const float* __restrict__ W2, u16* __restrict__ w2t,
                       const float* __restrict__ r2, u16* __restrict__ r2t,
                       const float* __restrict__ Wl, u16* __restrict__ wlt)
{
  int t = blockIdx.x*256 + threadIdx.x;
  if (t < 1048576){ out[t] = bl[t&63]; return; }
  t -= 1048576;
  if (t < 131072){ mkey[t] = 0u; return; }
  t -= 131072;
  if (t < 131072){ denom[t] = 0.f; return; }
  t -= 131072;
  if (t < 65536){ // w2t[o][k] = W_tp2[k][o], row stride 2048B
    int o = t & 511, kc = t >> 9;
    u32x4 v;
    v.x = pk2(W2[(size_t)(kc*8+0)*512+o], W2[(size_t)(kc*8+1)*512+o]);
    v.y = pk2(W2[(size_t)(kc*8+2)*512+o], W2[(size_t)(kc*8+3)*512+o]);
    v.z = pk2(W2[(size_t)(kc*8+4)*512+o], W2[(size_t)(kc*8+5)*512+o]);
    v.w = pk2(W2[(size_t)(kc*8+6)*512+o], W2[(size_t)(kc*8+7)*512+o]);
    *(u32x4*)((char*)w2t + (size_t)o*2048 + kc*16) = v;
    return;
  }
  t -= 65536;
  if (t < 4096){ // r2t[o][k] = r2[k][o], row stride 128B
    int o = t & 511, kc = t >> 9;
    u32x4 v;
    v.x = pk2(r2[(size_t)(kc*8+0)*512+o], r2[(size_t)(kc*8+1)*512+o]);
    v.y = pk2(r2[(size_t)(kc*8+2)*512+o], r2[(size_t)(kc*8+3)*512+o]);
    v.z = pk2(r2[(size_t)(kc*8+4)*512+o], r2[(size_t)(kc*8+5)*512+o]);
    v.w = pk2(r2[(size_t)(kc*8+6)*512+o], r2[(size_t)(kc*8+7)*512+o]);
    *(u32x4*)((char*)r2t + (size_t)o*128 + kc*16) = v;
    return;
  }
  t -= 4096;
  { // wlt[j][k] = W_lin[k][j], row stride 1024B
    int j = t & 63, kc = t >> 6;
    u32x4 v;
    v.x = pk2(Wl[(size_t)(kc*8+0)*64+j], Wl[(size_t)(kc*8+1)*64+j]);
    v.y = pk2(Wl[(size_t)(kc*8+2)*64+j], Wl[(size_t)(kc*8+3)*64+j]);
    v.z = pk2(Wl[(size_t)(kc*8+4)*64+j], Wl[(size_t)(kc*8+5)*64+j]);
    v.w = pk2(Wl[(size_t)(kc*8+6)*64+j], Wl[(size_t)(kc*8+7)*64+j]);
    *(u32x4*)((char*)wlt + (size_t)j*1024 + kc*16) = v;
  }
}

// ---------------------------------------------------------------------------
#define GEMV4(ACC, X, WBASE)                                                       \
  { const float* w_ = (WBASE);                                                     \
    _Pragma("unroll") for (int j=0;j<64;j++) ACC[j] = fmaf((X).x, w_[j],     ACC[j]); \
    _Pragma("unroll") for (int j=0;j<64;j++) ACC[j] = fmaf((X).y, w_[64+j],  ACC[j]); \
    _Pragma("unroll") for (int j=0;j<64;j++) ACC[j] = fmaf((X).z, w_[128+j], ACC[j]); \
    _Pragma("unroll") for (int j=0;j<64;j++) ACC[j] = fmaf((X).w, w_[192+j], ACC[j]); }

__global__ __launch_bounds__(256) void k_msg(
    const float* __restrict__ nf, const float* __restrict__ eleg,
    const int* __restrict__ esrc, const int* __restrict__ edst,
    const float* __restrict__ Wp, const float* __restrict__ bp,
    const float* __restrict__ r1, const float* __restrict__ rb1,
    u16* __restrict__ msgb, u16* __restrict__ hgb)
{
  const int e = blockIdx.x*256 + threadIdx.x;
  const int src = esrc[e];
  const int dst = edst[e];
  const float4* sr4 = (const float4*)(nf + (size_t)src*64);
  const float4* dr4 = (const float4*)(nf + (size_t)dst*64);
  const float4* er4 = (const float4*)(eleg + (size_t)e*64);

  float acc[64];
  #pragma unroll
  for (int j=0;j<64;j++) acc[j] = bp[j];
  for (int ic=0; ic<16; ++ic){ float4 x = sr4[ic]; GEMV4(acc, x, Wp + ic*256); }
  for (int ic=0; ic<16; ++ic){ float4 x = dr4[ic]; GEMV4(acc, x, Wp + 4096 + ic*256); }
  for (int ic=0; ic<16; ++ic){ float4 x = er4[ic]; GEMV4(acc, x, Wp + 8192 + ic*256); }
  {
    u32x4* md = (u32x4*)(msgb + (size_t)e*64);
    #pragma unroll
    for (int c=0;c<8;c++){
      u32x4 v;
      v.x = cvtpk(acc[8*c+0],acc[8*c+1]); v.y = cvtpk(acc[8*c+2],acc[8*c+3]);
      v.z = cvtpk(acc[8*c+4],acc[8*c+5]); v.w = cvtpk(acc[8*c+6],acc[8*c+7]);
      md[c] = v;
    }
  }
  // h_gate = silu(ele@r1 + rb1)
  #pragma unroll
  for (int j=0;j<64;j++) acc[j] = rb1[j];
  for (int ic=0; ic<16; ++ic){ float4 x = er4[ic]; GEMV4(acc, x, r1 + ic*256); }
  #pragma unroll
  for (int j=0;j<64;j++) acc[j] = acc[j] / (1.f + __expf(-acc[j]));
  {
    u32x4* hd = (u32x4*)(hgb + (size_t)e*64);
    #pragma unroll
    for (int c=0;c<8;c++){
      u32x4 v;
      v.x = cvtpk(acc[8*c+0],acc[8*c+1]); v.y = cvtpk(acc[8*c+2],acc[8*c+3]);
      v.z = cvtpk(acc[8*c+4],acc[8*c+5]); v.w = cvtpk(acc[8*c+6],acc[8*c+7]);
      hd[c] = v;
    }
  }
}

__global__ __launch_bounds__(256) void k_attn(
    const float* __restrict__ eleg, const int* __restrict__ edst,
    const float* __restrict__ a1, const float* __restrict__ ab1,
    const float* __restrict__ g1, const float* __restrict__ be1,
    const float* __restrict__ a2, const float* __restrict__ ab2,
    const float* __restrict__ g2, const float* __restrict__ be2,
    const float* __restrict__ a3, const float* __restrict__ ab3,
    float* __restrict__ eab, u32* __restrict__ mkey)
{
  const int e = blockIdx.x*256 + threadIdx.x;
  const int dst = edst[e];
  const float4* er4 = (const float4*)(eleg + (size_t)e*64);

  // u1 = silu(LN(ele@a1 + ab1, g1, be1))
  float u[64];
  #pragma unroll
  for (int j=0;j<64;j++) u[j] = ab1[j];
  for (int ic=0; ic<16; ++ic){ float4 x = er4[ic]; GEMV4(u, x, a1 + ic*256); }
  {
    float s = 0.f;
    #pragma unroll
    for (int j=0;j<64;j++) s += u[j];
    float mu = s * 0.015625f;
    float s2 = 0.f;
    #pragma unroll
    for (int j=0;j<64;j++){ float d = u[j]-mu; s2 = fmaf(d,d,s2); }
    float rs = rsqrtf(s2*0.015625f + 1e-6f);
    #pragma unroll
    for (int j=0;j<64;j++){
      float y = (u[j]-mu)*rs*g1[j] + be1[j];
      u[j] = y / (1.f + __expf(-y));
    }
  }
  // u2 = silu(LN(u1@a2 + ab2, g2, be2))   (static indexing: full unroll)
  float v[64];
  #pragma unroll
  for (int j=0;j<64;j++) v[j] = ab2[j];
  #pragma unroll
  for (int i=0;i<64;i++){
    float x = u[i];
    const float* w = a2 + i*64;
    #pragma unroll
    for (int j=0;j<64;j++) v[j] = fmaf(x, w[j], v[j]);
  }
  {
    float s = 0.f;
    #pragma unroll
    for (int j=0;j<64;j++) s += v[j];
    float mu = s * 0.015625f;
    float s2 = 0.f;
    #pragma unroll
    for (int j=0;j<64;j++){ float d = v[j]-mu; s2 = fmaf(d,d,s2); }
    float rs = rsqrtf(s2*0.015625f + 1e-6f);
    #pragma unroll
    for (int j=0;j<64;j++){
      float y = (v[j]-mu)*rs*g2[j] + be2[j];
      v[j] = y / (1.f + __expf(-y));
    }
  }
  // logits
  float l[8];
  #pragma unroll
  for (int h=0;h<8;h++) l[h] = ab3[h];
  #pragma unroll
  for (int i=0;i<64;i++){
    float x = v[i];
    #pragma unroll
    for (int h=0;h<8;h++) l[h] = fmaf(x, a3[i*8+h], l[h]);
  }
  float4* ld = (float4*)(eab + (size_t)e*8);
  ld[0] = make_float4(l[0],l[1],l[2],l[3]);
  ld[1] = make_float4(l[4],l[5],l[6],l[7]);
  #pragma unroll
  for (int h=0;h<8;h++){
    u32 b = __float_as_uint(l[h]);
    u32 k = (b & 0x80000000u) ? ~b : (b | 0x80000000u);
    atomicMax(&mkey[(size_t)dst*8 + h], k);
  }
}

// ---------------------------------------------------------------------------
__global__ void k_ea(const int* __restrict__ edst, float* __restrict__ eab,
                     const u32* __restrict__ mkey, float* __restrict__ denom)
{
  int e = blockIdx.x*256 + threadIdx.x;
  int dst = edst[e];
  float4 l0 = ((const float4*)(eab + (size_t)e*8))[0];
  float4 l1 = ((const float4*)(eab + (size_t)e*8))[1];
  uint4 k0 = ((const uint4*)(mkey + (size_t)dst*8))[0];
  uint4 k1 = ((const uint4*)(mkey + (size_t)dst*8))[1];
  float e0 = __expf(l0.x - decm(k0.x));
  float e1 = __expf(l0.y - decm(k0.y));
  float e2 = __expf(l0.z - decm(k0.z));
  float e3 = __expf(l0.w - decm(k0.w));
  float e4 = __expf(l1.x - decm(k1.x));
  float e5 = __expf(l1.y - decm(k1.y));
  float e6 = __expf(l1.z - decm(k1.z));
  float e7 = __expf(l1.w - decm(k1.w));
  ((float4*)(eab + (size_t)e*8))[0] = make_float4(e0,e1,e2,e3);
  ((float4*)(eab + (size_t)e*8))[1] = make_float4(e4,e5,e6,e7);
  float* dn = denom + (size_t)dst*8;
  atomAddF(dn+0,e0); atomAddF(dn+1,e1); atomAddF(dn+2,e2); atomAddF(dn+3,e3);
  atomAddF(dn+4,e4); atomAddF(dn+5,e5); atomAddF(dn+6,e6); atomAddF(dn+7,e7);
}

__global__ void k_norm(const int* __restrict__ edst, float* __restrict__ eab,
                       const float* __restrict__ denom)
{
  int e = blockIdx.x*256 + threadIdx.x;
  int dst = edst[e];
  float4 a0 = ((const float4*)(eab + (size_t)e*8))[0];
  float4 a1 = ((const float4*)(eab + (size_t)e*8))[1];
  float4 d0 = ((const float4*)(denom + (size_t)dst*8))[0];
  float4 d1 = ((const float4*)(denom + (size_t)dst*8))[1];
  ((float4*)(eab + (size_t)e*8))[0] = make_float4(a0.x/d0.x, a0.y/d0.y, a0.z/d0.z, a0.w/d0.w);
  ((float4*)(eab + (size_t)e*8))[1] = make_float4(a1.x/d1.x, a1.y/d1.y, a1.z/d1.z, a1.w/d1.w);
}

// ---------------------------------------------------------------------------
// Fused kernel. 512 thr = 8 waves; wave (wm=wave>>2, wn=wave&3) owns a
// 64e x 32o sub-tile of each 128x128 (e x o) col-block. Double-buffered
// A/B with prefetch-distance-1: one __syncthreads per K-slice, loads issued
// a full loop body ahead of the barrier that consumes them.
#define FORM_A(KSP, AN) {                                                        \
  float f0_ = bf2f((u16)((mrow[KSP]>>mshift)&0xFFFFu));                          \
  u32x4 w0_, w1_;                                                                \
  w0_.x=cvtpk(f0_*shr[0], f0_*shr[1]);  w0_.y=cvtpk(f0_*shr[2], f0_*shr[3]);     \
  w0_.z=cvtpk(f0_*shr[4], f0_*shr[5]);  w0_.w=cvtpk(f0_*shr[6], f0_*shr[7]);     \
  w1_.x=cvtpk(f0_*shr[8], f0_*shr[9]);  w1_.y=cvtpk(f0_*shr[10],f0_*shr[11]);    \
  w1_.z=cvtpk(f0_*shr[12],f0_*shr[13]); w1_.w=cvtpk(f0_*shr[14],f0_*shr[15]);    \
  char* b_ = (AN) + erow*128; int r7_ = erow&7;                                  \
  *(u32x4*)(b_ + (((t4*2+0)^r7_)*16)) = w0_;                                     \
  *(u32x4*)(b_ + (((t4*2+1)^r7_)*16)) = w1_; }

#define STAGE_B(KSP, BN) {                                                       \
  _Pragma("unroll")                                                              \
  for (int c_=0;c_<2;c_++){                                                      \
    int cid_=c_*512+tid, row_=cid_>>3, ch_=cid_&7;                               \
    gl2lds((const char*)w2t + (size_t)(j0+row_)*2048 + (KSP)*128 + ((ch_^(row_&7))*16), \
           (BN) + c_*8192 + wub);                                                \
  } }

__global__ __launch_bounds__(512,2) void k_fused(
    const u16* __restrict__ msgb, const float* __restrict__ shg,
    const u16* __restrict__ w2t, const u16* __restrict__ hgb,
    const u16* __restrict__ r2t, const float* __restrict__ rb2,
    const float* __restrict__ alpha, const u16* __restrict__ wlt,
    const int* __restrict__ edst, float* __restrict__ out)
{
  __shared__ char lds[65536];
  const int tid = threadIdx.x;
  const int e0 = blockIdx.x*128;
  const int wave = tid>>6, lane = tid&63;
  const int wm = wave>>2, wn = wave&3;
  const int wub = (tid&448)*16;     // wave-uniform LDS chunk base for gl2lds
  char* A0 = lds;
  char* A1 = lds+16384;
  char* B0 = lds+32768;
  char* B1 = lds+49152;

  const int erow = tid>>2, t4 = tid&3;
  const int et = e0 + erow;
  u32 mrow[16];
  {
    const u32* mp32 = (const u32*)(msgb + (size_t)et*64);
    #pragma unroll
    for (int ks=0; ks<16; ++ks) mrow[ks] = mp32[ks*2 + (t4>>1)];
  }
  const int mshift = (t4&1)*16;
  float shr[16];
  {
    const float4* sp = (const float4*)(shg + (size_t)et*16);
    float4 s0=sp[0], s1=sp[1], s2=sp[2], s3=sp[3];
    shr[0]=s0.x; shr[1]=s0.y; shr[2]=s0.z; shr[3]=s0.w;
    shr[4]=s1.x; shr[5]=s1.y; shr[6]=s1.z; shr[7]=s1.w;
    shr[8]=s2.x; shr[9]=s2.y; shr[10]=s2.z; shr[11]=s2.w;
    shr[12]=s3.x; shr[13]=s3.y; shr[14]=s3.z; shr[15]=s3.w;
  }

  f32x4 acc_o[4];
  #pragma unroll
  for (int n=0;n<4;n++) acc_o[n] = (f32x4){0.f,0.f,0.f,0.f};

  #pragma unroll 1
  for (int jb=0; jb<4; ++jb){
    const int j0 = jb*128;
    __syncthreads();                 // prior jb's vs-tile reads done
    // ---- stage scale-GEMM operands: hgb [128][64] -> A0, r2t slice -> B0
    #pragma unroll
    for (int c=0;c<2;c++){
      int cid=c*512+tid, row=cid>>3, ch=cid&7;
      gl2lds((const char*)hgb + (size_t)(e0+row)*128 + ((ch^(row&7))*16),
             A0 + c*8192 + wub);
    }
    #pragma unroll
    for (int c=0;c<2;c++){
      int cid=c*512+tid, row=cid>>3, ch=cid&7;
      gl2lds((const char*)r2t + (size_t)(j0+row)*128 + ((ch^(row&7))*16),
             B0 + c*8192 + wub);
    }
    __syncthreads();

    // ---- scale GEMM (K=64) -> scale[4][2] regs ----
    f32x4 scale[4][2];
    {
      f32x4 accs[4][2];
      #pragma unroll
      for (int a=0;a<4;a++){ accs[a][0]=(f32x4){0.f,0.f,0.f,0.f}; accs[a][1]=(f32x4){0.f,0.f,0.f,0.f}; }
      #pragma unroll
      for (int kk=0;kk<2;kk++){
        short8 af[4], bfv[2];
        int kc = kk*4 + (lane>>4);
        #pragma unroll
        for (int mt=0;mt<4;mt++){
          int r = wm*64 + mt*16 + (lane&15);
          af[mt] = *(const short8*)(A0 + r*128 + ((kc ^ (r&7))*16));
        }
        #pragma unroll
        for (int nt=0;nt<2;nt++){
          int r = wn*32 + nt*16 + (lane&15);
          bfv[nt] = *(const short8*)(B0 + r*128 + ((kc ^ (r&7))*16));
        }
        #pragma unroll
        for (int mt=0;mt<4;mt++)
          #pragma unroll
          for (int nt=0;nt<2;nt++)
            accs[mt][nt] = __builtin_amdgcn_mfma_f32_16x16x32_bf16(af[mt], bfv[nt], accs[mt][nt], 0,0,0);
      }
      const int h = jb*2 + (wn>>1);
      float alv[4][4];
      #pragma unroll
      for (int mt=0;mt<4;mt++)
        #pragma unroll
        for (int q=0;q<4;q++){
          int row = wm*64 + mt*16 + (lane>>4)*4 + q;
          alv[mt][q] = alpha[(size_t)(e0+row)*8 + h];
        }
      float rbv[2];
      #pragma unroll
      for (int nt=0;nt<2;nt++) rbv[nt] = rb2[j0 + wn*32 + nt*16 + (lane&15)];
      #pragma unroll
      for (int mt=0;mt<4;mt++)
        #pragma unroll
        for (int nt=0;nt<2;nt++)
          #pragma unroll
          for (int q=0;q<4;q++)
            scale[mt][nt][q] = (accs[mt][nt][q] + rbv[nt]) * alv[mt][q];
    }
    __syncthreads();                 // scale reads done; A0/B0 reusable

    // ---- value GEMM prologue: A(0)->A0, B(0)->B0 ----
    FORM_A(0, A0);
    STAGE_B(0, B0);
    __syncthreads();

    // ---- value GEMM main loop: dbuf, prefetch-distance 1, 1 barrier/ks ----
    f32x4 accv[4][2];
    #pragma unroll
    for (int a=0;a<4;a++){ accv[a][0]=(f32x4){0.f,0.f,0.f,0.f}; accv[a][1]=(f32x4){0.f,0.f,0.f,0.f}; }

    #pragma unroll 2
    for (int ks=0; ks<16; ++ks){
      char* Ac = (ks&1) ? A1 : A0;
      char* Bc = (ks&1) ? B1 : B0;
      char* An = (ks&1) ? A0 : A1;
      char* Bn = (ks&1) ? B0 : B1;
      if (ks < 15){
        STAGE_B(ks+1, Bn);          // prefetch B(ks+1) (in flight across body)
        FORM_A(ks+1, An);           // form A(ks+1) (VALU + ds_write, overlaps)
      }
      #pragma unroll
      for (int kk=0;kk<2;kk++){
        short8 af[4], bfv[2];
        int kc = kk*4 + (lane>>4);
        #pragma unroll
        for (int mt=0;mt<4;mt++){
          int r = wm*64 + mt*16 + (lane&15);
          af[mt] = *(const short8*)(Ac + r*128 + ((kc ^ (r&7))*16));
        }
        #pragma unroll
        for (int nt=0;nt<2;nt++){
          int r = wn*32 + nt*16 + (lane&15);
          bfv[nt] = *(const short8*)(Bc + r*128 + ((kc ^ (r&7))*16));
        }
        __builtin_amdgcn_s_setprio(1);
        #pragma unroll
        for (int mt=0;mt<4;mt++)
          #pragma unroll
          for (int nt=0;nt<2;nt++)
            accv[mt][nt] = __builtin_amdgcn_mfma_f32_16x16x32_bf16(af[mt], bfv[nt], accv[mt][nt], 0,0,0);
        __builtin_amdgcn_s_setprio(0);
      }
      __syncthreads();               // drains: B(ks+1) landed, A(ks+1) written,
                                     // all frag reads of Ac/Bc complete
    }

    // ---- vs = accv*scale -> LDS tile [128][128] bf16 (32KB = A0+A1) ----
    #pragma unroll
    for (int mt=0;mt<4;mt++)
      #pragma unroll
      for (int nt=0;nt<2;nt++){
        int col = wn*32 + nt*16 + (lane&15);
        int c16 = col>>3, cby = (col&7)*2;
        #pragma unroll
        for (int q=0;q<4;q++){
          int row = wm*64 + mt*16 + (lane>>4)*4 + q;
          *(u16*)(lds + row*256 + ((c16 ^ ((row&7)<<1))*16) + cby) =
              f2bf(accv[mt][nt][q] * scale[mt][nt][q]);
        }
      }
    __syncthreads();

    // ---- partial vs@W_lin (K=128 this jb), accumulate across jb ----
    #pragma unroll
    for (int kk=0;kk<4;kk++){
      short8 a2f;
      {
        int r = wave*16 + (lane&15);
        int kc = kk*4 + (lane>>4);
        a2f = *(const short8*)(lds + r*256 + ((kc ^ ((r&7)<<1))*16));
      }
      #pragma unroll
      for (int nt=0;nt<4;nt++){
        int j = nt*16 + (lane&15);
        int k = j0 + kk*32 + (lane>>4)*8;
        short8 b2f = *(const short8*)((const char*)wlt + (size_t)j*1024 + (size_t)k*2);
        acc_o[nt] = __builtin_amdgcn_mfma_f32_16x16x32_bf16(a2f, b2f, acc_o[nt], 0,0,0);
      }
    }
    // (jb-top __syncthreads protects the vs tile until next staging)
  }

  // ---- scatter into out[dst] ----
  #pragma unroll
  for (int q=0;q<4;q++){
    int r = wave*16 + (lane>>4)*4 + q;
    int n = edst[e0 + r];
    float* basep = out + (size_t)n*64;
    #pragma unroll
    for (int nt=0;nt<4;nt++){
      int col = nt*16 + (lane&15);
      atomAddF(basep + col, acc_o[nt][q]);
    }
  }
}

// ---------------------------------------------------------------------------
extern "C" void kernel_launch(void* const* d_in, const int* in_sizes, int n_in,
                              void* d_out, int out_size, void* d_ws, size_t ws_size,
                              hipStream_t stream)
{
  const float* nf  = (const float*)d_in[0];
  const float* shg = (const float*)d_in[1];
  const float* ele = (const float*)d_in[2];
  const int* esrc  = (const int*)d_in[3];
  const int* edst  = (const int*)d_in[4];
  const float* Wp  = (const float*)d_in[6];
  const float* bp  = (const float*)d_in[7];
  const float* W2  = (const float*)d_in[8];
  const float* r1  = (const float*)d_in[9];
  const float* rb1 = (const float*)d_in[10];
  const float* r2  = (const float*)d_in[11];
  const float* rb2 = (const float*)d_in[12];
  const float* a1  = (const float*)d_in[13];
  const float* ab1 = (const float*)d_in[14];
  const float* g1  = (const float*)d_in[15];
  const float* be1 = (const float*)d_in[16];
  const float* a2  = (const float*)d_in[17];
  const float* ab2 = (const float*)d_in[18];
  const float* g2  = (const float*)d_in[19];
  const float* be2 = (const float*)d_in[20];
  const float* a3  = (const float*)d_in[21];
  const float* ab3 = (const float*)d_in[22];
  const float* Wl  = (const float*)d_in[23];
  const float* bl  = (const float*)d_in[24];
  float* out = (float*)d_out;
  char* ws = (char*)d_ws;

  u16* msgb    = (u16*)(ws + 0);            // E*64 bf16 = 32MB
  u16* hgb     = (u16*)(ws + 33554432);     // E*64 bf16 = 32MB
  float* eab   = (float*)(ws + 67108864);   // E*8 f32 = 8MB (logits->ea->alpha)
  u32* mkey    = (u32*)(ws + 75497472);     // N*8 u32 = 512KB
  float* denom = (float*)(ws + 76021760);   // N*8 f32 = 512KB
  u16* w2t     = (u16*)(ws + 76546048);     // 512x1024 bf16 = 1MB
  u16* r2t     = (u16*)(ws + 77594624);     // 512x64 bf16 = 64KB
  u16* wlt     = (u16*)(ws + 77660160);     // 64x512 bf16 = 64KB
  // total ~74.1 MB

  k_prep<<<5408,256,0,stream>>>(out, bl, mkey, denom, W2, w2t, r2, r2t, Wl, wlt);
  k_msg<<<1024,256,0,stream>>>(nf, ele, esrc, edst, Wp, bp, r1, rb1, msgb, hgb);
  k_attn<<<1024,256,0,stream>>>(ele, edst, a1, ab1, g1, be1, a2, ab2, g2, be2,
                                a3, ab3, eab, mkey);
  k_ea<<<1024,256,0,stream>>>(edst, eab, mkey, denom);
  k_norm<<<1024,256,0,stream>>>(edst, eab, denom);
  k_fused<<<2048,512,0,stream>>>(msgb, shg, w2t, hgb, r2t, rb2, eab, wlt, edst, out);
}